// Round 4
// baseline (1276.890 us; speedup 1.0000x reference)
//
#include <hip/hip_runtime.h>
#include <hip/hip_bf16.h>

// Model dims
#define BB 4
#define TT 1024
#define DM 512
#define HF 2048
#define NL 6
#define SW 64

constexpr float EMB_SCALE = 0.04419417382415922f; // 1/sqrt(512)

typedef __attribute__((ext_vector_type(8))) short short8v;
typedef __attribute__((ext_vector_type(4))) float f32x4;

__device__ inline unsigned short f32_to_bf16(float x) {
  union { float f; unsigned u; } c; c.f = x;
  unsigned r = c.u + 0x7fffu + ((c.u >> 16) & 1u);
  return (unsigned short)(r >> 16);
}

__device__ inline void gload16(const void* g, void* l) {
  __builtin_amdgcn_global_load_lds(
      (const __attribute__((address_space(1))) void*)g,
      (__attribute__((address_space(3))) void*)l, 16, 0, 0);
}

// ---------------- elementwise kernels ----------------

__global__ __launch_bounds__(256) void scale_pos_k(const float* __restrict__ pos,
                                                   float* __restrict__ posS) {
  int i = blockIdx.x * 256 + threadIdx.x;
  posS[i] = pos[i] * EMB_SCALE;
}

__global__ __launch_bounds__(256) void embed_k(const int* __restrict__ x,
                                               const float* __restrict__ tok,
                                               const float* __restrict__ posS,
                                               float* __restrict__ h) {
  int i = blockIdx.x * 256 + threadIdx.x;
  int d = i & (DM - 1);
  int bt = i >> 9;
  int t = bt & (TT - 1);
  h[i] = tok[(size_t)x[bt] * DM + d] * EMB_SCALE + posS[t * DM + d];
}

// emb = h + pos (f32 + bf16 copies)
__global__ __launch_bounds__(256) void add_pos_k(const float* __restrict__ h,
                                                 const float* __restrict__ posS,
                                                 float* __restrict__ emb,
                                                 unsigned short* __restrict__ embb) {
  int i = blockIdx.x * 256 + threadIdx.x;
  int d = i & (DM - 1);
  int t = (i >> 9) & (TT - 1);
  float e = h[i] + posS[t * DM + d];
  emb[i] = e;
  embb[i] = f32_to_bf16(e);
}

// ---------------- weight transpose + bf16 convert ----------------
// W: [L][K][N] f32  ->  Wt: [L][N][K] bf16
__global__ __launch_bounds__(256) void transpose_w_k(const float* __restrict__ W,
                                                     unsigned short* __restrict__ Wt,
                                                     int K, int N) {
  __shared__ float tile[32][33];
  int l = blockIdx.z;
  const float* Wl = W + (size_t)l * K * N;
  unsigned short* Wtl = Wt + (size_t)l * K * N;
  int k0 = blockIdx.x * 32, n0 = blockIdx.y * 32;
  int tc = threadIdx.x & 31, tr = threadIdx.x >> 5; // tr 0..7
#pragma unroll
  for (int i = 0; i < 4; ++i) {
    int r = tr + i * 8;
    tile[r][tc] = Wl[(size_t)(k0 + r) * N + n0 + tc];
  }
  __syncthreads();
#pragma unroll
  for (int i = 0; i < 4; ++i) {
    int r = tr + i * 8;
    Wtl[(size_t)(n0 + r) * K + k0 + tc] = f32_to_bf16(tile[tc][r]);
  }
}

// ---------------- MFMA GEMM: C = A @ Bt^T + bias ----------------
// A: [M,K] bf16, Bt: [N,K] bf16, 64x64x64 tile, 4 waves (2x2), 16x16x32 MFMA.
// LDS granule swizzle: granule p holds data (r=p>>3, kb=(p&7)^(r&7)).
template <int OUT_BF16_RELU>
__global__ __launch_bounds__(256) void mfma_gemm_k(
    const unsigned short* __restrict__ A,
    const unsigned short* __restrict__ Bt,
    const float* __restrict__ bias,
    float* __restrict__ Cf,
    unsigned short* __restrict__ Cb,
    int M, int N, int K) {
  __shared__ __align__(16) unsigned short Als[64 * 64];
  __shared__ __align__(16) unsigned short Bls[64 * 64];

  const int tid = threadIdx.x;
  const int lane = tid & 63;
  const int wid = tid >> 6;
  const int wm = wid & 1, wn = wid >> 1;
  const int brow = blockIdx.y * 64;
  const int bcol = blockIdx.x * 64;

  f32x4 acc[2][2] = {};

  // staging: wave wid issues loads L0=2*wid, L1=2*wid+1 (64 granules each)
  int p0 = wid * 128 + lane;
  int r0 = p0 >> 3, kb0 = (p0 & 7) ^ (r0 & 7);
  int p1 = p0 + 64;
  int r1 = p1 >> 3, kb1 = (p1 & 7) ^ (r1 & 7);

  const unsigned short* Ag0 = A + (size_t)(brow + r0) * K + kb0 * 8;
  const unsigned short* Ag1 = A + (size_t)(brow + r1) * K + kb1 * 8;
  const unsigned short* Bg0 = Bt + (size_t)(bcol + r0) * K + kb0 * 8;
  const unsigned short* Bg1 = Bt + (size_t)(bcol + r1) * K + kb1 * 8;

  unsigned short* Alp0 = Als + wid * 1024;
  unsigned short* Alp1 = Als + wid * 1024 + 512;
  unsigned short* Blp0 = Bls + wid * 1024;
  unsigned short* Blp1 = Bls + wid * 1024 + 512;

  const int fr = lane & 15;  // m/n within fragment
  const int kg = lane >> 4;  // k-group 0..3

  for (int k0 = 0; k0 < K; k0 += 64) {
    gload16(Ag0 + k0, Alp0);
    gload16(Ag1 + k0, Alp1);
    gload16(Bg0 + k0, Blp0);
    gload16(Bg1 + k0, Blp1);
    __syncthreads();
#pragma unroll
    for (int mk = 0; mk < 2; ++mk) {
      int kb = mk * 4 + kg;
      short8v af[2], bf[2];
#pragma unroll
      for (int i = 0; i < 2; ++i) {
        int ra = wm * 32 + i * 16 + fr;
        int pa = ra * 8 + (kb ^ (ra & 7));
        af[i] = *(const short8v*)(Als + pa * 8);
        int rb = wn * 32 + i * 16 + fr;
        int pb = rb * 8 + (kb ^ (rb & 7));
        bf[i] = *(const short8v*)(Bls + pb * 8);
      }
#pragma unroll
      for (int i = 0; i < 2; ++i)
#pragma unroll
        for (int j = 0; j < 2; ++j)
          acc[i][j] = __builtin_amdgcn_mfma_f32_16x16x32_bf16(af[i], bf[j], acc[i][j], 0, 0, 0);
    }
    __syncthreads();
  }

#pragma unroll
  for (int j = 0; j < 2; ++j) {
    int col = bcol + wn * 32 + j * 16 + fr;
    float bv = bias[col];
#pragma unroll
    for (int i = 0; i < 2; ++i) {
      int rowb = brow + wm * 32 + i * 16 + kg * 4;
#pragma unroll
      for (int r = 0; r < 4; ++r) {
        float v = acc[i][j][r] + bv;
        if (OUT_BF16_RELU) {
          v = fmaxf(v, 0.f);
          Cb[(size_t)(rowb + r) * N + col] = f32_to_bf16(v);
        } else {
          Cf[(size_t)(rowb + r) * N + col] = v;
        }
      }
    }
  }
}

// ---------------- column max over t (for ek stabilization) ----------------

__global__ __launch_bounds__(256) void colmax1_k(const float* __restrict__ k,
                                                 float* __restrict__ pmax) {
  int d = blockIdx.x * 256 + threadIdx.x;
  int b = blockIdx.y;
  int z = blockIdx.z;
  const float* p = k + ((size_t)b * TT + z * 128) * DM + d;
  float m = -1e30f;
#pragma unroll 8
  for (int t = 0; t < 128; ++t) m = fmaxf(m, p[(size_t)t * DM]);
  pmax[((size_t)z * BB + b) * DM + d] = m;
}

__global__ __launch_bounds__(256) void colmax2_k(const float* __restrict__ pmax,
                                                 float* __restrict__ kmax) {
  int d = blockIdx.x * 256 + threadIdx.x;
  int b = blockIdx.y;
  float m = -1e30f;
#pragma unroll
  for (int z = 0; z < 8; ++z) m = fmaxf(m, pmax[((size_t)z * BB + b) * DM + d]);
  kmax[b * DM + d] = m;
}

// ek = exp(k - kmax), ekv = ek * v   (in place over k, v)
__global__ __launch_bounds__(256) void exp_kv_k(float* __restrict__ k,
                                                float* __restrict__ v,
                                                const float* __restrict__ kmax) {
  size_t i = (size_t)blockIdx.x * 256 + threadIdx.x;
  int d = (int)(i & (DM - 1));
  int b = (int)(i >> 19);
  float e = __expf(k[i] - kmax[b * DM + d]);
  k[i] = e;
  v[i] = e * v[i];
}

// ew[t][j] = exp(w_bias[t, t-j] - rowmax) for j=0..min(t,63); 0 beyond
__global__ void ew_prep_k(const float* __restrict__ wb, float* __restrict__ ew) {
  int t = blockIdx.x;
  int j = threadIdx.x;  // 64 threads
  int u = t - j;
  bool valid = (u >= 0);
  float w = valid ? wb[(size_t)t * TT + u] : -1e30f;
  float m = w;
#pragma unroll
  for (int off = 32; off; off >>= 1) m = fmaxf(m, __shfl_xor(m, off));
  ew[t * SW + j] = valid ? __expf(w - m) : 0.f;
}

// y = sigmoid(q) * num/(den+1e-9); output bf16
__global__ __launch_bounds__(256) void aft_agg_k(const float* __restrict__ ek,
                                                 const float* __restrict__ ekv,
                                                 const float* __restrict__ ew,
                                                 const float* __restrict__ q,
                                                 unsigned short* __restrict__ yb) {
  int bt = blockIdx.x;
  int b = bt >> 10;
  int t = bt & (TT - 1);
  __shared__ float ews[SW];
  if (threadIdx.x < SW) ews[threadIdx.x] = ew[t * SW + threadIdx.x];
  __syncthreads();
  int jmax = min(t, SW - 1);
  size_t base = ((size_t)b * TT + t) * DM;
#pragma unroll
  for (int half = 0; half < 2; ++half) {
    int d = threadIdx.x + half * 256;
    const float* pek = ek + base + d;
    const float* pev = ekv + base + d;
    float num = 0.f, den = 0.f;
    for (int j = 0; j <= jmax; ++j) {
      float w = ews[j];
      den += w * pek[-(size_t)j * DM];
      num += w * pev[-(size_t)j * DM];
    }
    float qv = q[base + d];
    float sig = 1.f / (1.f + __expf(-qv));
    yb[base + d] = f32_to_bf16(sig * num / (den + 1e-9f));
  }
}

// out = LN(X + Y) * g + b ; one wave per row of 512; optional bf16 copy
__global__ __launch_bounds__(256) void add_ln_k(const float* __restrict__ X,
                                                const float* __restrict__ Y,
                                                const float* __restrict__ g,
                                                const float* __restrict__ bb,
                                                float* __restrict__ out,
                                                unsigned short* __restrict__ outb) {
  int row = blockIdx.x * 4 + (threadIdx.x >> 6);
  int lane = threadIdx.x & 63;
  const float* x = X + (size_t)row * DM;
  const float* y = Y + (size_t)row * DM;
  float4 v0 = *(const float4*)(x + lane * 8);
  float4 v1 = *(const float4*)(x + lane * 8 + 4);
  float4 w0 = *(const float4*)(y + lane * 8);
  float4 w1 = *(const float4*)(y + lane * 8 + 4);
  float vals[8] = {v0.x + w0.x, v0.y + w0.y, v0.z + w0.z, v0.w + w0.w,
                   v1.x + w1.x, v1.y + w1.y, v1.z + w1.z, v1.w + w1.w};
  float s = 0.f, s2 = 0.f;
#pragma unroll
  for (int i = 0; i < 8; ++i) {
    s += vals[i];
    s2 += vals[i] * vals[i];
  }
#pragma unroll
  for (int off = 32; off; off >>= 1) {
    s += __shfl_xor(s, off);
    s2 += __shfl_xor(s2, off);
  }
  float mean = s * (1.f / DM);
  float var = s2 * (1.f / DM) - mean * mean;
  float rs = rsqrtf(var + 1e-5f);
  float o[8];
#pragma unroll
  for (int i = 0; i < 8; ++i) {
    int d = lane * 8 + i;
    o[i] = (vals[i] - mean) * rs * g[d] + bb[d];
  }
  float* op = out + (size_t)row * DM + lane * 8;
  *(float4*)(op) = make_float4(o[0], o[1], o[2], o[3]);
  *(float4*)(op + 4) = make_float4(o[4], o[5], o[6], o[7]);
  if (outb) {
    unsigned short ob[8];
#pragma unroll
    for (int i = 0; i < 8; ++i) ob[i] = f32_to_bf16(o[i]);
    *(short8v*)(outb + (size_t)row * DM + lane * 8) = *(short8v*)ob;
  }
}

// ---------------- launch ----------------

extern "C" void kernel_launch(void* const* d_in, const int* in_sizes, int n_in,
                              void* d_out, int out_size, void* d_ws, size_t ws_size,
                              hipStream_t stream) {
  const int* x = (const int*)d_in[0];
  const float* tok_emb = (const float*)d_in[1];
  const float* pos_emb = (const float*)d_in[2];
  const float* Wq = (const float*)d_in[3];
  const float* bq = (const float*)d_in[4];
  const float* Wk = (const float*)d_in[5];
  const float* bk = (const float*)d_in[6];
  const float* Wv = (const float*)d_in[7];
  const float* bv = (const float*)d_in[8];
  const float* Wo = (const float*)d_in[9];
  const float* bo = (const float*)d_in[10];
  const float* w_bias = (const float*)d_in[11];
  const float* ln_g = (const float*)d_in[12];
  const float* ln_b = (const float*)d_in[13];
  const float* W1 = (const float*)d_in[14];
  const float* b1 = (const float*)d_in[15];
  const float* W2 = (const float*)d_in[16];
  const float* b2 = (const float*)d_in[17];

  const size_t BTD = (size_t)BB * TT * DM;  // 2097152
  char* ws = (char*)d_ws;
  size_t o = 0;
  auto alloc_f = [&](size_t n) { float* p = (float*)(ws + o); o += n * 4; return p; };
  auto alloc_h = [&](size_t n) { unsigned short* p = (unsigned short*)(ws + o); o += n * 2; return p; };

  float* posS = alloc_f((size_t)TT * DM);
  float* h    = alloc_f(BTD);
  float* emb  = alloc_f(BTD);
  float* q    = alloc_f(BTD);
  float* k    = alloc_f(BTD);   // ek; later aliased as 'a' (O-GEMM out)
  float* v    = alloc_f(BTD);   // ekv; later aliased as 'f2'
  float* attn = alloc_f(BTD);
  float* ew   = alloc_f((size_t)TT * SW);
  float* kmax = alloc_f((size_t)BB * DM);
  float* pmax = alloc_f((size_t)8 * BB * DM);
  unsigned short* embb  = alloc_h(BTD);
  unsigned short* yb    = alloc_h(BTD);
  unsigned short* attnb = alloc_h(BTD);
  unsigned short* f1b   = alloc_h((size_t)BB * TT * HF);
  unsigned short* Wqt = alloc_h((size_t)NL * DM * DM);
  unsigned short* Wkt = alloc_h((size_t)NL * DM * DM);
  unsigned short* Wvt = alloc_h((size_t)NL * DM * DM);
  unsigned short* Wot = alloc_h((size_t)NL * DM * DM);
  unsigned short* W1t = alloc_h((size_t)NL * DM * HF);
  unsigned short* W2t = alloc_h((size_t)NL * HF * DM);

  const int EW_BLOCKS = (int)(BTD / 256);  // 8192

  // weight transposes (bf16)
  transpose_w_k<<<dim3(DM / 32, DM / 32, NL), 256, 0, stream>>>(Wq, Wqt, DM, DM);
  transpose_w_k<<<dim3(DM / 32, DM / 32, NL), 256, 0, stream>>>(Wk, Wkt, DM, DM);
  transpose_w_k<<<dim3(DM / 32, DM / 32, NL), 256, 0, stream>>>(Wv, Wvt, DM, DM);
  transpose_w_k<<<dim3(DM / 32, DM / 32, NL), 256, 0, stream>>>(Wo, Wot, DM, DM);
  transpose_w_k<<<dim3(DM / 32, HF / 32, NL), 256, 0, stream>>>(W1, W1t, DM, HF);
  transpose_w_k<<<dim3(HF / 32, DM / 32, NL), 256, 0, stream>>>(W2, W2t, HF, DM);

  scale_pos_k<<<TT * DM / 256, 256, 0, stream>>>(pos_emb, posS);
  embed_k<<<EW_BLOCKS, 256, 0, stream>>>(x, tok_emb, posS, h);

  for (int i = 0; i < NL; ++i) {
    const unsigned short* Wqt_i = Wqt + (size_t)i * DM * DM;
    const unsigned short* Wkt_i = Wkt + (size_t)i * DM * DM;
    const unsigned short* Wvt_i = Wvt + (size_t)i * DM * DM;
    const unsigned short* Wot_i = Wot + (size_t)i * DM * DM;
    const float* bq_i = bq + (size_t)i * DM;
    const float* bk_i = bk + (size_t)i * DM;
    const float* bv_i = bv + (size_t)i * DM;
    const float* bo_i = bo + (size_t)i * DM;
    const float* wb_i = w_bias + (size_t)i * TT * TT;
    const float* g_i = ln_g + (size_t)i * DM;
    const float* b_i = ln_b + (size_t)i * DM;
    const unsigned short* W1t_i = W1t + (size_t)i * DM * HF;
    const float* b1_i = b1 + (size_t)i * HF;
    const unsigned short* W2t_i = W2t + (size_t)i * HF * DM;
    const float* b2_i = b2 + (size_t)i * DM;

    add_pos_k<<<EW_BLOCKS, 256, 0, stream>>>(h, posS, emb, embb);

    dim3 gq(DM / 64, BB * TT / 64);  // (8, 64)
    mfma_gemm_k<0><<<gq, 256, 0, stream>>>(embb, Wqt_i, bq_i, q, nullptr, BB * TT, DM, DM);
    mfma_gemm_k<0><<<gq, 256, 0, stream>>>(embb, Wkt_i, bk_i, k, nullptr, BB * TT, DM, DM);
    mfma_gemm_k<0><<<gq, 256, 0, stream>>>(embb, Wvt_i, bv_i, v, nullptr, BB * TT, DM, DM);

    colmax1_k<<<dim3(2, BB, 8), 256, 0, stream>>>(k, pmax);
    colmax2_k<<<dim3(2, BB), 256, 0, stream>>>(pmax, kmax);
    exp_kv_k<<<EW_BLOCKS, 256, 0, stream>>>(k, v, kmax);
    ew_prep_k<<<TT, 64, 0, stream>>>(wb_i, ew);
    aft_agg_k<<<BB * TT, 256, 0, stream>>>(k, v, ew, q, yb);

    // O-GEMM into k (free), then attn LN
    mfma_gemm_k<0><<<gq, 256, 0, stream>>>(yb, Wot_i, bo_i, k, nullptr, BB * TT, DM, DM);
    add_ln_k<<<BB * TT / 4, 256, 0, stream>>>(k, emb, g_i, b_i, attn, attnb);

    // FFN
    dim3 gf1(HF / 64, BB * TT / 64);  // (32, 64)
    mfma_gemm_k<1><<<gf1, 256, 0, stream>>>(attnb, W1t_i, b1_i, nullptr, f1b, BB * TT, HF, DM);
    mfma_gemm_k<0><<<gq, 256, 0, stream>>>(f1b, W2t_i, b2_i, v, nullptr, BB * TT, DM, HF);

    float* hout = (i == NL - 1) ? (float*)d_out : h;
    add_ln_k<<<BB * TT / 4, 256, 0, stream>>>(v, attn, g_i, b_i, hout, nullptr);
  }
}

// Round 5
// 1113.535 us; speedup vs baseline: 1.1467x; 1.1467x over previous
//
#include <hip/hip_runtime.h>
#include <hip/hip_bf16.h>

// Model dims
#define BB 4
#define TT 1024
#define DM 512
#define HF 2048
#define NL 6
#define SW 64

constexpr float EMB_SCALE = 0.04419417382415922f; // 1/sqrt(512)

typedef __attribute__((ext_vector_type(8))) short short8v;
typedef __attribute__((ext_vector_type(4))) float f32x4;

__device__ inline unsigned short f32_to_bf16(float x) {
  union { float f; unsigned u; } c; c.f = x;
  unsigned r = c.u + 0x7fffu + ((c.u >> 16) & 1u);
  return (unsigned short)(r >> 16);
}

__device__ inline void gload16(const void* g, void* l) {
  __builtin_amdgcn_global_load_lds(
      (const __attribute__((address_space(1))) void*)g,
      (__attribute__((address_space(3))) void*)l, 16, 0, 0);
}

// ---------------- elementwise kernels ----------------

__global__ __launch_bounds__(256) void scale_pos_k(const float* __restrict__ pos,
                                                   float* __restrict__ posS) {
  int i = blockIdx.x * 256 + threadIdx.x;
  posS[i] = pos[i] * EMB_SCALE;
}

__global__ __launch_bounds__(256) void embed_k(const int* __restrict__ x,
                                               const float* __restrict__ tok,
                                               const float* __restrict__ posS,
                                               float* __restrict__ h) {
  int i = blockIdx.x * 256 + threadIdx.x;
  int d = i & (DM - 1);
  int bt = i >> 9;
  int t = bt & (TT - 1);
  h[i] = tok[(size_t)x[bt] * DM + d] * EMB_SCALE + posS[t * DM + d];
}

// emb = h + pos (f32 + bf16 copies)
__global__ __launch_bounds__(256) void add_pos_k(const float* __restrict__ h,
                                                 const float* __restrict__ posS,
                                                 float* __restrict__ emb,
                                                 unsigned short* __restrict__ embb) {
  int i = blockIdx.x * 256 + threadIdx.x;
  int d = i & (DM - 1);
  int t = (i >> 9) & (TT - 1);
  float e = h[i] + posS[t * DM + d];
  emb[i] = e;
  embb[i] = f32_to_bf16(e);
}

// ---------------- weight transpose + bf16 convert ----------------
// W: [L][K][N] f32 -> Wt rows at (out_ro + n) of a [out_nrows][K] bf16 slab
// (slab for layer l begins at Wt + l*out_ls)
__global__ __launch_bounds__(256) void transpose_w_k(const float* __restrict__ W,
                                                     unsigned short* __restrict__ Wt,
                                                     int K, int N,
                                                     long out_ls, int out_ro) {
  __shared__ float tile[32][33];
  int l = blockIdx.z;
  const float* Wl = W + (size_t)l * K * N;
  unsigned short* Wtl = Wt + (size_t)l * out_ls;
  int k0 = blockIdx.x * 32, n0 = blockIdx.y * 32;
  int tc = threadIdx.x & 31, tr = threadIdx.x >> 5; // tr 0..7
#pragma unroll
  for (int i = 0; i < 4; ++i) {
    int r = tr + i * 8;
    tile[r][tc] = Wl[(size_t)(k0 + r) * N + n0 + tc];
  }
  __syncthreads();
#pragma unroll
  for (int i = 0; i < 4; ++i) {
    int r = tr + i * 8;
    Wtl[(size_t)(out_ro + n0 + r) * K + k0 + tc] = f32_to_bf16(tile[tc][r]);
  }
}

// ---------------- MFMA GEMM 64x64 tile (proven R4 structure) ----------------
// A: [M,K] bf16, Bt: [N,K] bf16. MODE 0: f32 out. MODE 1: relu+bf16 out.
template <int MODE>
__global__ __launch_bounds__(256) void gemm64_k(
    const unsigned short* __restrict__ A,
    const unsigned short* __restrict__ Bt,
    const float* __restrict__ bias,
    float* __restrict__ Cf,
    unsigned short* __restrict__ Cb,
    int M, int N, int K) {
  __shared__ __align__(16) unsigned short Als[64 * 64];
  __shared__ __align__(16) unsigned short Bls[64 * 64];

  const int tid = threadIdx.x;
  const int lane = tid & 63;
  const int wid = tid >> 6;
  const int wm = wid & 1, wn = wid >> 1;
  const int brow = blockIdx.y * 64;
  const int bcol = blockIdx.x * 64;

  f32x4 acc[2][2] = {};

  int p0 = wid * 128 + lane;
  int r0 = p0 >> 3, kb0 = (p0 & 7) ^ (r0 & 7);
  int p1 = p0 + 64;
  int r1 = p1 >> 3, kb1 = (p1 & 7) ^ (r1 & 7);

  const unsigned short* Ag0 = A + (size_t)(brow + r0) * K + kb0 * 8;
  const unsigned short* Ag1 = A + (size_t)(brow + r1) * K + kb1 * 8;
  const unsigned short* Bg0 = Bt + (size_t)(bcol + r0) * K + kb0 * 8;
  const unsigned short* Bg1 = Bt + (size_t)(bcol + r1) * K + kb1 * 8;

  unsigned short* Alp0 = Als + wid * 1024;
  unsigned short* Alp1 = Als + wid * 1024 + 512;
  unsigned short* Blp0 = Bls + wid * 1024;
  unsigned short* Blp1 = Bls + wid * 1024 + 512;

  const int fr = lane & 15;
  const int kg = lane >> 4;

  for (int k0 = 0; k0 < K; k0 += 64) {
    gload16(Ag0 + k0, Alp0);
    gload16(Ag1 + k0, Alp1);
    gload16(Bg0 + k0, Blp0);
    gload16(Bg1 + k0, Blp1);
    __syncthreads();
#pragma unroll
    for (int mk = 0; mk < 2; ++mk) {
      int kb = mk * 4 + kg;
      short8v af[2], bf[2];
#pragma unroll
      for (int i = 0; i < 2; ++i) {
        int ra = wm * 32 + i * 16 + fr;
        int pa = ra * 8 + (kb ^ (ra & 7));
        af[i] = *(const short8v*)(Als + pa * 8);
        int rb = wn * 32 + i * 16 + fr;
        int pb = rb * 8 + (kb ^ (rb & 7));
        bf[i] = *(const short8v*)(Bls + pb * 8);
      }
#pragma unroll
      for (int i = 0; i < 2; ++i)
#pragma unroll
        for (int j = 0; j < 2; ++j)
          acc[i][j] = __builtin_amdgcn_mfma_f32_16x16x32_bf16(af[i], bf[j], acc[i][j], 0, 0, 0);
    }
    __syncthreads();
  }

#pragma unroll
  for (int j = 0; j < 2; ++j) {
    int col = bcol + wn * 32 + j * 16 + fr;
    float bv = bias[col];
#pragma unroll
    for (int i = 0; i < 2; ++i) {
      int rowb = brow + wm * 32 + i * 16 + kg * 4;
#pragma unroll
      for (int r = 0; r < 4; ++r) {
        float v = acc[i][j][r] + bv;
        if (MODE == 1) {
          v = fmaxf(v, 0.f);
          Cb[(size_t)(rowb + r) * N + col] = f32_to_bf16(v);
        } else {
          Cf[(size_t)(rowb + r) * N + col] = v;
        }
      }
    }
  }
}

// ---------------- MFMA GEMM 128x128 tile, 4 waves, 4x4 frags/wave ----------
// MODE 0: f32 out (stride N). MODE 1: relu+bf16 out. MODE 2: qkv column split
// (N=1536; cols [0,512)->o0, [512,1024)->o1, [1024,1536)->o2, stride 512).
template <int MODE>
__global__ __launch_bounds__(256) void gemm128_k(
    const unsigned short* __restrict__ A,
    const unsigned short* __restrict__ Bt,
    const float* __restrict__ b0,
    const float* __restrict__ b1,
    const float* __restrict__ b2,
    float* __restrict__ o0,
    float* __restrict__ o1,
    float* __restrict__ o2,
    unsigned short* __restrict__ Cb,
    int M, int N, int K) {
  __shared__ __align__(16) unsigned short Als[128 * 64];
  __shared__ __align__(16) unsigned short Bls[128 * 64];

  const int tid = threadIdx.x;
  const int lane = tid & 63;
  const int wid = tid >> 6;
  const int wm = wid & 1, wn = wid >> 1;
  const int brow = blockIdx.y * 128;
  const int bcol = blockIdx.x * 128;

  f32x4 acc[4][4] = {};

  // staging: 1024 granules per array; wave wid covers p in [wid*256, wid*256+256)
  int rr[4], kk[4];
  const unsigned short* Ag[4];
  const unsigned short* Bg[4];
#pragma unroll
  for (int c = 0; c < 4; ++c) {
    int p = wid * 256 + c * 64 + lane;
    rr[c] = p >> 3;
    kk[c] = (p & 7) ^ (rr[c] & 7);
    Ag[c] = A + (size_t)(brow + rr[c]) * K + kk[c] * 8;
    Bg[c] = Bt + (size_t)(bcol + rr[c]) * K + kk[c] * 8;
  }

  const int fr = lane & 15;
  const int kg = lane >> 4;

  for (int k0 = 0; k0 < K; k0 += 64) {
#pragma unroll
    for (int c = 0; c < 4; ++c) {
      gload16(Ag[c] + k0, Als + wid * 2048 + c * 512);
      gload16(Bg[c] + k0, Bls + wid * 2048 + c * 512);
    }
    __syncthreads();
#pragma unroll
    for (int mk = 0; mk < 2; ++mk) {
      int kb = mk * 4 + kg;
      short8v af[4], bf[4];
#pragma unroll
      for (int i = 0; i < 4; ++i) {
        int ra = wm * 64 + i * 16 + fr;
        int pa = ra * 8 + (kb ^ (ra & 7));
        af[i] = *(const short8v*)(Als + pa * 8);
        int rb = wn * 64 + i * 16 + fr;
        int pb = rb * 8 + (kb ^ (rb & 7));
        bf[i] = *(const short8v*)(Bls + pb * 8);
      }
#pragma unroll
      for (int i = 0; i < 4; ++i)
#pragma unroll
        for (int j = 0; j < 4; ++j)
          acc[i][j] = __builtin_amdgcn_mfma_f32_16x16x32_bf16(af[i], bf[j], acc[i][j], 0, 0, 0);
    }
    __syncthreads();
  }

#pragma unroll
  for (int j = 0; j < 4; ++j) {
    int colg = bcol + wn * 64 + j * 16 + fr;
    float bv;
    float* op;
    int col;
    if (MODE == 2) {
      int sel = colg >> 9;
      col = colg & 511;
      bv = (sel == 0) ? b0[col] : (sel == 1) ? b1[col] : b2[col];
      op = (sel == 0) ? o0 : (sel == 1) ? o1 : o2;
    } else {
      col = colg;
      bv = b0[col];
      op = o0;
    }
    const int ostride = (MODE == 2) ? DM : N;
#pragma unroll
    for (int i = 0; i < 4; ++i) {
      int rowb = brow + wm * 64 + i * 16 + kg * 4;
#pragma unroll
      for (int r = 0; r < 4; ++r) {
        float v = acc[i][j][r] + bv;
        if (MODE == 1) {
          v = fmaxf(v, 0.f);
          Cb[(size_t)(rowb + r) * N + col] = f32_to_bf16(v);
        } else {
          op[(size_t)(rowb + r) * ostride + col] = v;
        }
      }
    }
  }
}

// ---------------- column max over t (for ek stabilization) ----------------

__global__ __launch_bounds__(256) void colmax1_k(const float* __restrict__ k,
                                                 float* __restrict__ pmax) {
  int d = blockIdx.x * 256 + threadIdx.x;
  int b = blockIdx.y;
  int z = blockIdx.z;
  const float* p = k + ((size_t)b * TT + z * 128) * DM + d;
  float m = -1e30f;
#pragma unroll 8
  for (int t = 0; t < 128; ++t) m = fmaxf(m, p[(size_t)t * DM]);
  pmax[((size_t)z * BB + b) * DM + d] = m;
}

__global__ __launch_bounds__(256) void colmax2_k(const float* __restrict__ pmax,
                                                 float* __restrict__ kmax) {
  int d = blockIdx.x * 256 + threadIdx.x;
  int b = blockIdx.y;
  float m = -1e30f;
#pragma unroll
  for (int z = 0; z < 8; ++z) m = fmaxf(m, pmax[((size_t)z * BB + b) * DM + d]);
  kmax[b * DM + d] = m;
}

// ek = exp(k - kmax), ekv = ek * v   (in place over k, v)
__global__ __launch_bounds__(256) void exp_kv_k(float* __restrict__ k,
                                                float* __restrict__ v,
                                                const float* __restrict__ kmax) {
  size_t i = (size_t)blockIdx.x * 256 + threadIdx.x;
  int d = (int)(i & (DM - 1));
  int b = (int)(i >> 19);
  float e = __expf(k[i] - kmax[b * DM + d]);
  k[i] = e;
  v[i] = e * v[i];
}

// ew[t][j] = exp(w_bias[t, t-j] - rowmax) for j=0..min(t,63); 0 beyond
__global__ void ew_prep_k(const float* __restrict__ wb, float* __restrict__ ew) {
  int t = blockIdx.x;
  int j = threadIdx.x;  // 64 threads
  int u = t - j;
  bool valid = (u >= 0);
  float w = valid ? wb[(size_t)t * TT + u] : -1e30f;
  float m = w;
#pragma unroll
  for (int off = 32; off; off >>= 1) m = fmaxf(m, __shfl_xor(m, off));
  ew[t * SW + j] = valid ? __expf(w - m) : 0.f;
}

// ---------------- tiled AFT aggregation ----------------
// block = (d-chunk 64, t-tile 64, b). Stage ek/ekv halo rows + ew in LDS.
// y = sigmoid(q) * num/(den+1e-9); output bf16.
#define AGG_ROWS 127  // 64 + 63 halo
#define AGG_LDS_BYTES ((AGG_ROWS * 64 * 2 + 64 * 64) * 4)

__global__ __launch_bounds__(256) void aft_agg_k(const float* __restrict__ ek,
                                                 const float* __restrict__ ekv,
                                                 const float* __restrict__ ew,
                                                 const float* __restrict__ q,
                                                 unsigned short* __restrict__ yb) {
  extern __shared__ float smem[];
  float* ekS = smem;                       // [127][64]
  float* evS = smem + AGG_ROWS * 64;       // [127][64]
  float* ewS = smem + AGG_ROWS * 64 * 2;   // [64][64]

  const int tid = threadIdx.x;
  const int d0 = blockIdx.x * 64;
  const int t0 = blockIdx.y * 64;
  const int b = blockIdx.z;

  // load ek/ekv halo window (zero-fill rows u<0); 2032 float4 per array
  const size_t rowbase = ((size_t)b * TT) * DM + d0;
  for (int idx = tid; idx < AGG_ROWS * 16; idx += 256) {
    int r = idx >> 4, c = idx & 15;
    int u = t0 - 63 + r;
    float4 ze = make_float4(0.f, 0.f, 0.f, 0.f);
    float4 va = (u >= 0) ? *(const float4*)(ek + rowbase + (size_t)u * DM + c * 4) : ze;
    float4 vb = (u >= 0) ? *(const float4*)(ekv + rowbase + (size_t)u * DM + c * 4) : ze;
    *(float4*)(ekS + r * 64 + c * 4) = va;
    *(float4*)(evS + r * 64 + c * 4) = vb;
  }
  // load ew rows t0..t0+63 (1024 float4)
  for (int idx = tid; idx < 1024; idx += 256) {
    int r = idx >> 4, c = idx & 15;
    *(float4*)(ewS + r * 64 + c * 4) = *(const float4*)(ew + (size_t)(t0 + r) * SW + c * 4);
  }
  __syncthreads();

  const int tx = tid & 63;
  const int ty = tid >> 6;
#pragma unroll
  for (int i = 0; i < 16; ++i) {
    int tl = ty * 16 + i;
    float num = 0.f, den = 0.f;
    // ew[t][j]==0 for j>t covers the t<63 edge (halo rows are zero-filled)
#pragma unroll 4
    for (int j = 0; j < 64; ++j) {
      float w = ewS[tl * 64 + j];
      int r = tl + 63 - j;
      den += w * ekS[r * 64 + tx];
      num += w * evS[r * 64 + tx];
    }
    size_t base = ((size_t)b * TT + t0 + tl) * DM + d0 + tx;
    float qv = q[base];
    float sig = 1.f / (1.f + __expf(-qv));
    yb[base] = f32_to_bf16(sig * num / (den + 1e-9f));
  }
}

// out = LN(X + Y) * g + b ; one wave per row of 512; optional bf16 copy
__global__ __launch_bounds__(256) void add_ln_k(const float* __restrict__ X,
                                                const float* __restrict__ Y,
                                                const float* __restrict__ g,
                                                const float* __restrict__ bb,
                                                float* __restrict__ out,
                                                unsigned short* __restrict__ outb) {
  int row = blockIdx.x * 4 + (threadIdx.x >> 6);
  int lane = threadIdx.x & 63;
  const float* x = X + (size_t)row * DM;
  const float* y = Y + (size_t)row * DM;
  float4 v0 = *(const float4*)(x + lane * 8);
  float4 v1 = *(const float4*)(x + lane * 8 + 4);
  float4 w0 = *(const float4*)(y + lane * 8);
  float4 w1 = *(const float4*)(y + lane * 8 + 4);
  float vals[8] = {v0.x + w0.x, v0.y + w0.y, v0.z + w0.z, v0.w + w0.w,
                   v1.x + w1.x, v1.y + w1.y, v1.z + w1.z, v1.w + w1.w};
  float s = 0.f, s2 = 0.f;
#pragma unroll
  for (int i = 0; i < 8; ++i) {
    s += vals[i];
    s2 += vals[i] * vals[i];
  }
#pragma unroll
  for (int off = 32; off; off >>= 1) {
    s += __shfl_xor(s, off);
    s2 += __shfl_xor(s2, off);
  }
  float mean = s * (1.f / DM);
  float var = s2 * (1.f / DM) - mean * mean;
  float rs = rsqrtf(var + 1e-5f);
  float o[8];
#pragma unroll
  for (int i = 0; i < 8; ++i) {
    int d = lane * 8 + i;
    o[i] = (vals[i] - mean) * rs * g[d] + bb[d];
  }
  float* op = out + (size_t)row * DM + lane * 8;
  *(float4*)(op) = make_float4(o[0], o[1], o[2], o[3]);
  *(float4*)(op + 4) = make_float4(o[4], o[5], o[6], o[7]);
  if (outb) {
    unsigned short ob[8];
#pragma unroll
    for (int i = 0; i < 8; ++i) ob[i] = f32_to_bf16(o[i]);
    *(short8v*)(outb + (size_t)row * DM + lane * 8) = *(short8v*)ob;
  }
}

// ---------------- launch ----------------

extern "C" void kernel_launch(void* const* d_in, const int* in_sizes, int n_in,
                              void* d_out, int out_size, void* d_ws, size_t ws_size,
                              hipStream_t stream) {
  const int* x = (const int*)d_in[0];
  const float* tok_emb = (const float*)d_in[1];
  const float* pos_emb = (const float*)d_in[2];
  const float* Wq = (const float*)d_in[3];
  const float* bq = (const float*)d_in[4];
  const float* Wk = (const float*)d_in[5];
  const float* bk = (const float*)d_in[6];
  const float* Wv = (const float*)d_in[7];
  const float* bv = (const float*)d_in[8];
  const float* Wo = (const float*)d_in[9];
  const float* bo = (const float*)d_in[10];
  const float* w_bias = (const float*)d_in[11];
  const float* ln_g = (const float*)d_in[12];
  const float* ln_b = (const float*)d_in[13];
  const float* W1 = (const float*)d_in[14];
  const float* b1 = (const float*)d_in[15];
  const float* W2 = (const float*)d_in[16];
  const float* b2 = (const float*)d_in[17];

  const size_t BTD = (size_t)BB * TT * DM;  // 2097152
  char* ws = (char*)d_ws;
  size_t o = 0;
  auto alloc_f = [&](size_t n) { float* p = (float*)(ws + o); o += n * 4; return p; };
  auto alloc_h = [&](size_t n) { unsigned short* p = (unsigned short*)(ws + o); o += n * 2; return p; };

  float* posS = alloc_f((size_t)TT * DM);
  float* h    = alloc_f(BTD);
  float* emb  = alloc_f(BTD);
  float* q    = alloc_f(BTD);
  float* k    = alloc_f(BTD);   // ek; later reused as O-GEMM out
  float* v    = alloc_f(BTD);   // ekv; later reused as FFN2 out
  float* attn = alloc_f(BTD);
  float* ew   = alloc_f((size_t)TT * SW);
  float* kmax = alloc_f((size_t)BB * DM);
  float* pmax = alloc_f((size_t)8 * BB * DM);
  unsigned short* embb  = alloc_h(BTD);
  unsigned short* yb    = alloc_h(BTD);
  unsigned short* attnb = alloc_h(BTD);
  unsigned short* f1b   = alloc_h((size_t)BB * TT * HF);
  unsigned short* Wqkvt = alloc_h((size_t)NL * 3 * DM * DM);  // [1536][512]/layer
  unsigned short* Wot = alloc_h((size_t)NL * DM * DM);
  unsigned short* W1t = alloc_h((size_t)NL * DM * HF);
  unsigned short* W2t = alloc_h((size_t)NL * HF * DM);

  const int EW_BLOCKS = (int)(BTD / 256);  // 8192

  // weight transposes (bf16)
  transpose_w_k<<<dim3(DM / 32, DM / 32, NL), 256, 0, stream>>>(Wq, Wqkvt, DM, DM, (long)3 * DM * DM, 0);
  transpose_w_k<<<dim3(DM / 32, DM / 32, NL), 256, 0, stream>>>(Wk, Wqkvt, DM, DM, (long)3 * DM * DM, DM);
  transpose_w_k<<<dim3(DM / 32, DM / 32, NL), 256, 0, stream>>>(Wv, Wqkvt, DM, DM, (long)3 * DM * DM, 2 * DM);
  transpose_w_k<<<dim3(DM / 32, DM / 32, NL), 256, 0, stream>>>(Wo, Wot, DM, DM, (long)DM * DM, 0);
  transpose_w_k<<<dim3(DM / 32, HF / 32, NL), 256, 0, stream>>>(W1, W1t, DM, HF, (long)DM * HF, 0);
  transpose_w_k<<<dim3(HF / 32, DM / 32, NL), 256, 0, stream>>>(W2, W2t, HF, DM, (long)HF * DM, 0);

  scale_pos_k<<<TT * DM / 256, 256, 0, stream>>>(pos_emb, posS);
  embed_k<<<EW_BLOCKS, 256, 0, stream>>>(x, tok_emb, posS, h);

  for (int i = 0; i < NL; ++i) {
    const unsigned short* Wqkvt_i = Wqkvt + (size_t)i * 3 * DM * DM;
    const unsigned short* Wot_i = Wot + (size_t)i * DM * DM;
    const float* bq_i = bq + (size_t)i * DM;
    const float* bk_i = bk + (size_t)i * DM;
    const float* bv_i = bv + (size_t)i * DM;
    const float* bo_i = bo + (size_t)i * DM;
    const float* wb_i = w_bias + (size_t)i * TT * TT;
    const float* g_i = ln_g + (size_t)i * DM;
    const float* b_i = ln_b + (size_t)i * DM;
    const unsigned short* W1t_i = W1t + (size_t)i * DM * HF;
    const float* b1_i = b1 + (size_t)i * HF;
    const unsigned short* W2t_i = W2t + (size_t)i * HF * DM;
    const float* b2_i = b2 + (size_t)i * DM;

    add_pos_k<<<EW_BLOCKS, 256, 0, stream>>>(h, posS, emb, embb);

    // fused QKV GEMM: [4096,512] x [1536,512]^T -> q,k,v
    gemm128_k<2><<<dim3(3 * DM / 128, BB * TT / 128), 256, 0, stream>>>(
        embb, Wqkvt_i, bq_i, bk_i, bv_i, q, k, v, nullptr, BB * TT, 3 * DM, DM);

    colmax1_k<<<dim3(2, BB, 8), 256, 0, stream>>>(k, pmax);
    colmax2_k<<<dim3(2, BB), 256, 0, stream>>>(pmax, kmax);
    exp_kv_k<<<EW_BLOCKS, 256, 0, stream>>>(k, v, kmax);
    ew_prep_k<<<TT, 64, 0, stream>>>(wb_i, ew);
    aft_agg_k<<<dim3(DM / 64, TT / 64, BB), 256, AGG_LDS_BYTES, stream>>>(k, v, ew, q, yb);

    // O-GEMM into k (free), then attn LN
    dim3 g64(DM / 64, BB * TT / 64);  // (8, 64)
    gemm64_k<0><<<g64, 256, 0, stream>>>(yb, Wot_i, bo_i, k, nullptr, BB * TT, DM, DM);
    add_ln_k<<<BB * TT / 4, 256, 0, stream>>>(k, emb, g_i, b_i, attn, attnb);

    // FFN
    gemm128_k<1><<<dim3(HF / 128, BB * TT / 128), 256, 0, stream>>>(
        attnb, W1t_i, b1_i, nullptr, nullptr, nullptr, nullptr, nullptr, f1b, BB * TT, HF, DM);
    gemm64_k<0><<<g64, 256, 0, stream>>>(f1b, W2t_i, b2_i, v, nullptr, BB * TT, DM, HF);

    float* hout = (i == NL - 1) ? (float*)d_out : h;
    add_ln_k<<<BB * TT / 4, 256, 0, stream>>>(v, attn, g_i, b_i, hout, nullptr);
  }
}

// Round 6
// 1105.098 us; speedup vs baseline: 1.1555x; 1.0076x over previous
//
#include <hip/hip_runtime.h>
#include <hip/hip_bf16.h>

// Model dims
#define BB 4
#define TT 1024
#define DM 512
#define HF 2048
#define NL 6
#define SW 64

constexpr float EMB_SCALE = 0.04419417382415922f; // 1/sqrt(512)

typedef __attribute__((ext_vector_type(8))) short short8v;
typedef __attribute__((ext_vector_type(4))) float f32x4;

__device__ inline unsigned short f32_to_bf16(float x) {
  union { float f; unsigned u; } c; c.f = x;
  unsigned r = c.u + 0x7fffu + ((c.u >> 16) & 1u);
  return (unsigned short)(r >> 16);
}

__device__ inline void gload16(const void* g, void* l) {
  __builtin_amdgcn_global_load_lds(
      (const __attribute__((address_space(1))) void*)g,
      (__attribute__((address_space(3))) void*)l, 16, 0, 0);
}

// ---------------- elementwise kernels ----------------

__global__ __launch_bounds__(256) void scale_pos_k(const float* __restrict__ pos,
                                                   float* __restrict__ posS) {
  int i = blockIdx.x * 256 + threadIdx.x;
  posS[i] = pos[i] * EMB_SCALE;
}

// emb = tok*scale + 2*posS (h + pos folded), f32 + bf16
__global__ __launch_bounds__(256) void embed_k(const int* __restrict__ x,
                                               const float* __restrict__ tok,
                                               const float* __restrict__ posS,
                                               float* __restrict__ emb,
                                               unsigned short* __restrict__ embb) {
  int i = blockIdx.x * 256 + threadIdx.x;
  int d = i & (DM - 1);
  int bt = i >> 9;
  int t = bt & (TT - 1);
  float e = tok[(size_t)x[bt] * DM + d] * EMB_SCALE + 2.f * posS[t * DM + d];
  emb[i] = e;
  embb[i] = f32_to_bf16(e);
}

// ---------------- weight transpose + bf16 convert ----------------
// W: [L][K][N] f32 -> Wt rows at (out_ro + n) of a bf16 slab (layer stride out_ls)
__global__ __launch_bounds__(256) void transpose_w_k(const float* __restrict__ W,
                                                     unsigned short* __restrict__ Wt,
                                                     int K, int N,
                                                     long out_ls, int out_ro) {
  __shared__ float tile[32][33];
  int l = blockIdx.z;
  const float* Wl = W + (size_t)l * K * N;
  unsigned short* Wtl = Wt + (size_t)l * out_ls;
  int k0 = blockIdx.x * 32, n0 = blockIdx.y * 32;
  int tc = threadIdx.x & 31, tr = threadIdx.x >> 5; // tr 0..7
#pragma unroll
  for (int i = 0; i < 4; ++i) {
    int r = tr + i * 8;
    tile[r][tc] = Wl[(size_t)(k0 + r) * N + n0 + tc];
  }
  __syncthreads();
#pragma unroll
  for (int i = 0; i < 4; ++i) {
    int r = tr + i * 8;
    Wtl[(size_t)(out_ro + n0 + r) * K + k0 + tc] = f32_to_bf16(tile[tc][r]);
  }
}

// ---------------- MFMA GEMM 128x128 tile, 4 waves, 4x4 frags/wave ----------
// MODE 1: relu+bf16 out. MODE 2: qkv column split (N=1536; stride 512 outs).
template <int MODE>
__global__ __launch_bounds__(256) void gemm128_k(
    const unsigned short* __restrict__ A,
    const unsigned short* __restrict__ Bt,
    const float* __restrict__ b0,
    const float* __restrict__ b1,
    const float* __restrict__ b2,
    float* __restrict__ o0,
    float* __restrict__ o1,
    float* __restrict__ o2,
    unsigned short* __restrict__ Cb,
    int M, int N, int K) {
  __shared__ __align__(16) unsigned short Als[128 * 64];
  __shared__ __align__(16) unsigned short Bls[128 * 64];

  const int tid = threadIdx.x;
  const int lane = tid & 63;
  const int wid = tid >> 6;
  const int wm = wid & 1, wn = wid >> 1;
  const int brow = blockIdx.y * 128;
  const int bcol = blockIdx.x * 128;

  f32x4 acc[4][4] = {};

  int rr[4], kk[4];
  const unsigned short* Ag[4];
  const unsigned short* Bg[4];
#pragma unroll
  for (int c = 0; c < 4; ++c) {
    int p = wid * 256 + c * 64 + lane;
    rr[c] = p >> 3;
    kk[c] = (p & 7) ^ (rr[c] & 7);
    Ag[c] = A + (size_t)(brow + rr[c]) * K + kk[c] * 8;
    Bg[c] = Bt + (size_t)(bcol + rr[c]) * K + kk[c] * 8;
  }

  const int fr = lane & 15;
  const int kg = lane >> 4;

  for (int k0 = 0; k0 < K; k0 += 64) {
#pragma unroll
    for (int c = 0; c < 4; ++c) {
      gload16(Ag[c] + k0, Als + wid * 2048 + c * 512);
      gload16(Bg[c] + k0, Bls + wid * 2048 + c * 512);
    }
    __syncthreads();
#pragma unroll
    for (int mk = 0; mk < 2; ++mk) {
      int kb = mk * 4 + kg;
      short8v af[4], bf[4];
#pragma unroll
      for (int i = 0; i < 4; ++i) {
        int ra = wm * 64 + i * 16 + fr;
        int pa = ra * 8 + (kb ^ (ra & 7));
        af[i] = *(const short8v*)(Als + pa * 8);
        int rb = wn * 64 + i * 16 + fr;
        int pb = rb * 8 + (kb ^ (rb & 7));
        bf[i] = *(const short8v*)(Bls + pb * 8);
      }
#pragma unroll
      for (int i = 0; i < 4; ++i)
#pragma unroll
        for (int j = 0; j < 4; ++j)
          acc[i][j] = __builtin_amdgcn_mfma_f32_16x16x32_bf16(af[i], bf[j], acc[i][j], 0, 0, 0);
    }
    __syncthreads();
  }

#pragma unroll
  for (int j = 0; j < 4; ++j) {
    int colg = bcol + wn * 64 + j * 16 + fr;
    float bv;
    float* op;
    int col;
    if (MODE == 2) {
      int sel = colg >> 9;
      col = colg & 511;
      bv = (sel == 0) ? b0[col] : (sel == 1) ? b1[col] : b2[col];
      op = (sel == 0) ? o0 : (sel == 1) ? o1 : o2;
    } else {
      col = colg;
      bv = b0[col];
      op = o0;
    }
    const int ostride = (MODE == 2) ? DM : N;
#pragma unroll
    for (int i = 0; i < 4; ++i) {
      int rowb = brow + wm * 64 + i * 16 + kg * 4;
#pragma unroll
      for (int r = 0; r < 4; ++r) {
        float v = acc[i][j][r] + bv;
        if (MODE == 1) {
          v = fmaxf(v, 0.f);
          Cb[(size_t)(rowb + r) * N + col] = f32_to_bf16(v);
        } else {
          op[(size_t)(rowb + r) * ostride + col] = v;
        }
      }
    }
  }
}

// ---------------- MFMA GEMM 128x64 tile (for N=512), 4 waves 2x2 ------------
// per wave: 64x32 out = 4x2 fragments. f32 out + bias.
__global__ __launch_bounds__(256) void gemmN64_k(
    const unsigned short* __restrict__ A,
    const unsigned short* __restrict__ Bt,
    const float* __restrict__ bias,
    float* __restrict__ Cf,
    int M, int N, int K) {
  __shared__ __align__(16) unsigned short Als[128 * 64];
  __shared__ __align__(16) unsigned short Bls[64 * 64];

  const int tid = threadIdx.x;
  const int lane = tid & 63;
  const int wid = tid >> 6;
  const int wm = wid & 1, wn = wid >> 1;
  const int brow = blockIdx.y * 128;
  const int bcol = blockIdx.x * 64;

  f32x4 acc[4][2] = {};

  int ra_[4], ka_[4], rb_[2], kb_[2];
  const unsigned short* Ag[4];
  const unsigned short* Bg[2];
#pragma unroll
  for (int c = 0; c < 4; ++c) {
    int p = wid * 256 + c * 64 + lane;
    ra_[c] = p >> 3;
    ka_[c] = (p & 7) ^ (ra_[c] & 7);
    Ag[c] = A + (size_t)(brow + ra_[c]) * K + ka_[c] * 8;
  }
#pragma unroll
  for (int c = 0; c < 2; ++c) {
    int p = wid * 128 + c * 64 + lane;
    rb_[c] = p >> 3;
    kb_[c] = (p & 7) ^ (rb_[c] & 7);
    Bg[c] = Bt + (size_t)(bcol + rb_[c]) * K + kb_[c] * 8;
  }

  const int fr = lane & 15;
  const int kg = lane >> 4;

  for (int k0 = 0; k0 < K; k0 += 64) {
#pragma unroll
    for (int c = 0; c < 4; ++c)
      gload16(Ag[c] + k0, Als + wid * 2048 + c * 512);
#pragma unroll
    for (int c = 0; c < 2; ++c)
      gload16(Bg[c] + k0, Bls + wid * 1024 + c * 512);
    __syncthreads();
#pragma unroll
    for (int mk = 0; mk < 2; ++mk) {
      int kb = mk * 4 + kg;
      short8v af[4], bf[2];
#pragma unroll
      for (int i = 0; i < 4; ++i) {
        int ra = wm * 64 + i * 16 + fr;
        int pa = ra * 8 + (kb ^ (ra & 7));
        af[i] = *(const short8v*)(Als + pa * 8);
      }
#pragma unroll
      for (int j = 0; j < 2; ++j) {
        int rb = wn * 32 + j * 16 + fr;
        int pb = rb * 8 + (kb ^ (rb & 7));
        bf[j] = *(const short8v*)(Bls + pb * 8);
      }
#pragma unroll
      for (int i = 0; i < 4; ++i)
#pragma unroll
        for (int j = 0; j < 2; ++j)
          acc[i][j] = __builtin_amdgcn_mfma_f32_16x16x32_bf16(af[i], bf[j], acc[i][j], 0, 0, 0);
    }
    __syncthreads();
  }

#pragma unroll
  for (int j = 0; j < 2; ++j) {
    int col = bcol + wn * 32 + j * 16 + fr;
    float bv = bias[col];
#pragma unroll
    for (int i = 0; i < 4; ++i) {
      int rowb = brow + wm * 64 + i * 16 + kg * 4;
#pragma unroll
      for (int r = 0; r < 4; ++r) {
        Cf[(size_t)(rowb + r) * N + col] = acc[i][j][r] + bv;
      }
    }
  }
}

// ---------------- column max over t (for ek stabilization) ----------------

__global__ __launch_bounds__(256) void colmax1_k(const float* __restrict__ k,
                                                 float* __restrict__ pmax) {
  int d = blockIdx.x * 256 + threadIdx.x;
  int b = blockIdx.y;
  int z = blockIdx.z;
  const float* p = k + ((size_t)b * TT + z * 128) * DM + d;
  float m = -1e30f;
#pragma unroll 8
  for (int t = 0; t < 128; ++t) m = fmaxf(m, p[(size_t)t * DM]);
  pmax[((size_t)z * BB + b) * DM + d] = m;
}

__global__ __launch_bounds__(256) void colmax2_k(const float* __restrict__ pmax,
                                                 float* __restrict__ kmax) {
  int d = blockIdx.x * 256 + threadIdx.x;
  int b = blockIdx.y;
  float m = -1e30f;
#pragma unroll
  for (int z = 0; z < 8; ++z) m = fmaxf(m, pmax[((size_t)z * BB + b) * DM + d]);
  kmax[b * DM + d] = m;
}

// ---------------- fused AFT aggregation ----------------
// block = (d-chunk 64, t-tile 64, b). Stages exp(k-kmax), exp*v halo + computes
// ew from w_bias in LDS. y = sigmoid(q)*num/(den+1e-9) -> bf16.
#define AGG_ROWS 127  // 64 + 63 halo
#define AGG_LDS_BYTES ((AGG_ROWS * 64 * 2 + 64 * 64) * 4)

__global__ __launch_bounds__(256) void aft_agg_k(const float* __restrict__ kr,
                                                 const float* __restrict__ vr,
                                                 const float* __restrict__ kmax,
                                                 const float* __restrict__ wb,
                                                 const float* __restrict__ q,
                                                 unsigned short* __restrict__ yb) {
  extern __shared__ float smem[];
  float* ekS = smem;                       // [127][64]
  float* evS = smem + AGG_ROWS * 64;       // [127][64]
  float* ewS = smem + AGG_ROWS * 64 * 2;   // [64][64]

  const int tid = threadIdx.x;
  const int d0 = blockIdx.x * 64;
  const int t0 = blockIdx.y * 64;
  const int b = blockIdx.z;

  // ---- ew rows t0..t0+63 from w_bias: tid = r*4 + qq, j = qq*16..+16
  {
    int r = tid >> 2, qq = tid & 3;
    int t = t0 + r;
    const float* wrow = wb + (size_t)t * TT + t;
    float vals[16];
    float m = -1e30f;
#pragma unroll
    for (int jj = 0; jj < 16; ++jj) {
      int j = qq * 16 + jj;
      bool valid = (t - j >= 0);
      vals[jj] = valid ? wrow[-j] : -1e30f;
      m = fmaxf(m, vals[jj]);
    }
    m = fmaxf(m, __shfl_xor(m, 1));
    m = fmaxf(m, __shfl_xor(m, 2));
#pragma unroll
    for (int jj = 0; jj < 16; ++jj) {
      int j = qq * 16 + jj;
      ewS[r * 64 + j] = (t - j >= 0) ? __expf(vals[jj] - m) : 0.f;
    }
  }

  // ---- stage ek = exp(k - kmax), ekv = ek*v over halo rows (zero-fill u<0)
  const size_t rowbase = ((size_t)b * TT) * DM + d0;
  for (int idx = tid; idx < AGG_ROWS * 16; idx += 256) {
    int r = idx >> 4, c = idx & 15;
    int u = t0 - 63 + r;
    float4 e4 = make_float4(0.f, 0.f, 0.f, 0.f);
    float4 g4 = make_float4(0.f, 0.f, 0.f, 0.f);
    if (u >= 0) {
      float4 k4 = *(const float4*)(kr + rowbase + (size_t)u * DM + c * 4);
      float4 v4 = *(const float4*)(vr + rowbase + (size_t)u * DM + c * 4);
      float4 km = *(const float4*)(kmax + (size_t)b * DM + d0 + c * 4);
      e4.x = __expf(k4.x - km.x); g4.x = e4.x * v4.x;
      e4.y = __expf(k4.y - km.y); g4.y = e4.y * v4.y;
      e4.z = __expf(k4.z - km.z); g4.z = e4.z * v4.z;
      e4.w = __expf(k4.w - km.w); g4.w = e4.w * v4.w;
    }
    *(float4*)(ekS + r * 64 + c * 4) = e4;
    *(float4*)(evS + r * 64 + c * 4) = g4;
  }
  __syncthreads();

  const int tx = tid & 63;
  const int ty = tid >> 6;
#pragma unroll
  for (int i = 0; i < 16; ++i) {
    int tl = ty * 16 + i;
    float num = 0.f, den = 0.f;
#pragma unroll 4
    for (int j = 0; j < 64; ++j) {
      float w = ewS[tl * 64 + j];
      int r = tl + 63 - j;
      den += w * ekS[r * 64 + tx];
      num += w * evS[r * 64 + tx];
    }
    size_t base = ((size_t)b * TT + t0 + tl) * DM + d0 + tx;
    float qv = q[base];
    float sig = 1.f / (1.f + __expf(-qv));
    yb[base] = f32_to_bf16(sig * num / (den + 1e-9f));
  }
}

// out = LN(X + Y) * g + b (+posS if ADDPOS); one wave per row of 512
template <int ADDPOS>
__global__ __launch_bounds__(256) void add_ln_k(const float* __restrict__ X,
                                                const float* __restrict__ Y,
                                                const float* __restrict__ g,
                                                const float* __restrict__ bb,
                                                const float* __restrict__ posS,
                                                float* __restrict__ out,
                                                unsigned short* __restrict__ outb) {
  int row = blockIdx.x * 4 + (threadIdx.x >> 6);
  int lane = threadIdx.x & 63;
  const float* x = X + (size_t)row * DM;
  const float* y = Y + (size_t)row * DM;
  float4 v0 = *(const float4*)(x + lane * 8);
  float4 v1 = *(const float4*)(x + lane * 8 + 4);
  float4 w0 = *(const float4*)(y + lane * 8);
  float4 w1 = *(const float4*)(y + lane * 8 + 4);
  float vals[8] = {v0.x + w0.x, v0.y + w0.y, v0.z + w0.z, v0.w + w0.w,
                   v1.x + w1.x, v1.y + w1.y, v1.z + w1.z, v1.w + w1.w};
  float s = 0.f, s2 = 0.f;
#pragma unroll
  for (int i = 0; i < 8; ++i) {
    s += vals[i];
    s2 += vals[i] * vals[i];
  }
#pragma unroll
  for (int off = 32; off; off >>= 1) {
    s += __shfl_xor(s, off);
    s2 += __shfl_xor(s2, off);
  }
  float mean = s * (1.f / DM);
  float var = s2 * (1.f / DM) - mean * mean;
  float rs = rsqrtf(var + 1e-5f);
  float o[8];
#pragma unroll
  for (int i = 0; i < 8; ++i) {
    int d = lane * 8 + i;
    o[i] = (vals[i] - mean) * rs * g[d] + bb[d];
  }
  if (ADDPOS) {
    const float* pr = posS + (size_t)(row & (TT - 1)) * DM + lane * 8;
#pragma unroll
    for (int i = 0; i < 8; ++i) o[i] += pr[i];
  }
  float* op = out + (size_t)row * DM + lane * 8;
  *(float4*)(op) = make_float4(o[0], o[1], o[2], o[3]);
  *(float4*)(op + 4) = make_float4(o[4], o[5], o[6], o[7]);
  if (outb) {
    unsigned short ob[8];
#pragma unroll
    for (int i = 0; i < 8; ++i) ob[i] = f32_to_bf16(o[i]);
    *(short8v*)(outb + (size_t)row * DM + lane * 8) = *(short8v*)ob;
  }
}

// ---------------- launch ----------------

extern "C" void kernel_launch(void* const* d_in, const int* in_sizes, int n_in,
                              void* d_out, int out_size, void* d_ws, size_t ws_size,
                              hipStream_t stream) {
  const int* x = (const int*)d_in[0];
  const float* tok_emb = (const float*)d_in[1];
  const float* pos_emb = (const float*)d_in[2];
  const float* Wq = (const float*)d_in[3];
  const float* bq = (const float*)d_in[4];
  const float* Wk = (const float*)d_in[5];
  const float* bk = (const float*)d_in[6];
  const float* Wv = (const float*)d_in[7];
  const float* bv = (const float*)d_in[8];
  const float* Wo = (const float*)d_in[9];
  const float* bo = (const float*)d_in[10];
  const float* w_bias = (const float*)d_in[11];
  const float* ln_g = (const float*)d_in[12];
  const float* ln_b = (const float*)d_in[13];
  const float* W1 = (const float*)d_in[14];
  const float* b1 = (const float*)d_in[15];
  const float* W2 = (const float*)d_in[16];
  const float* b2 = (const float*)d_in[17];

  const size_t BTD = (size_t)BB * TT * DM;  // 2097152
  char* ws = (char*)d_ws;
  size_t o = 0;
  auto alloc_f = [&](size_t n) { float* p = (float*)(ws + o); o += n * 4; return p; };
  auto alloc_h = [&](size_t n) { unsigned short* p = (unsigned short*)(ws + o); o += n * 2; return p; };

  float* posS = alloc_f((size_t)TT * DM);
  float* emb  = alloc_f(BTD);
  float* q    = alloc_f(BTD);   // q; reused as O-GEMM out
  float* k    = alloc_f(BTD);   // raw k; reused as FFN2 out
  float* v    = alloc_f(BTD);   // raw v
  float* attn = alloc_f(BTD);
  float* kmax = alloc_f((size_t)BB * DM);
  float* pmax = alloc_f((size_t)8 * BB * DM);
  unsigned short* embb  = alloc_h(BTD);
  unsigned short* yb    = alloc_h(BTD);
  unsigned short* attnb = alloc_h(BTD);
  unsigned short* f1b   = alloc_h((size_t)BB * TT * HF);
  unsigned short* Wqkvt = alloc_h((size_t)NL * 3 * DM * DM);
  unsigned short* Wot = alloc_h((size_t)NL * DM * DM);
  unsigned short* W1t = alloc_h((size_t)NL * DM * HF);
  unsigned short* W2t = alloc_h((size_t)NL * HF * DM);

  const int EW_BLOCKS = (int)(BTD / 256);  // 8192

  // weight transposes (bf16)
  transpose_w_k<<<dim3(DM / 32, DM / 32, NL), 256, 0, stream>>>(Wq, Wqkvt, DM, DM, (long)3 * DM * DM, 0);
  transpose_w_k<<<dim3(DM / 32, DM / 32, NL), 256, 0, stream>>>(Wk, Wqkvt, DM, DM, (long)3 * DM * DM, DM);
  transpose_w_k<<<dim3(DM / 32, DM / 32, NL), 256, 0, stream>>>(Wv, Wqkvt, DM, DM, (long)3 * DM * DM, 2 * DM);
  transpose_w_k<<<dim3(DM / 32, DM / 32, NL), 256, 0, stream>>>(Wo, Wot, DM, DM, (long)DM * DM, 0);
  transpose_w_k<<<dim3(DM / 32, HF / 32, NL), 256, 0, stream>>>(W1, W1t, DM, HF, (long)DM * HF, 0);
  transpose_w_k<<<dim3(HF / 32, DM / 32, NL), 256, 0, stream>>>(W2, W2t, HF, DM, (long)HF * DM, 0);

  scale_pos_k<<<TT * DM / 256, 256, 0, stream>>>(pos_emb, posS);
  embed_k<<<EW_BLOCKS, 256, 0, stream>>>(x, tok_emb, posS, emb, embb);

  for (int i = 0; i < NL; ++i) {
    const unsigned short* Wqkvt_i = Wqkvt + (size_t)i * 3 * DM * DM;
    const unsigned short* Wot_i = Wot + (size_t)i * DM * DM;
    const float* bq_i = bq + (size_t)i * DM;
    const float* bk_i = bk + (size_t)i * DM;
    const float* bv_i = bv + (size_t)i * DM;
    const float* bo_i = bo + (size_t)i * DM;
    const float* wb_i = w_bias + (size_t)i * TT * TT;
    const float* g_i = ln_g + (size_t)i * DM;
    const float* b_i = ln_b + (size_t)i * DM;
    const unsigned short* W1t_i = W1t + (size_t)i * DM * HF;
    const float* b1_i = b1 + (size_t)i * HF;
    const unsigned short* W2t_i = W2t + (size_t)i * HF * DM;
    const float* b2_i = b2 + (size_t)i * DM;

    // fused QKV GEMM: [4096,512] x [1536,512]^T -> q,k,v (f32)
    gemm128_k<2><<<dim3(3 * DM / 128, BB * TT / 128), 256, 0, stream>>>(
        embb, Wqkvt_i, bq_i, bk_i, bv_i, q, k, v, nullptr, BB * TT, 3 * DM, DM);

    colmax1_k<<<dim3(2, BB, 8), 256, 0, stream>>>(k, pmax);
    colmax2_k<<<dim3(2, BB), 256, 0, stream>>>(pmax, kmax);

    // fused AFT: exp + window weights + aggregation + sigmoid gate
    aft_agg_k<<<dim3(DM / 64, TT / 64, BB), 256, AGG_LDS_BYTES, stream>>>(
        k, v, kmax, wb_i, q, yb);

    // O-GEMM into q (free), then attn LN
    gemmN64_k<<<dim3(DM / 64, BB * TT / 128), 256, 0, stream>>>(
        yb, Wot_i, bo_i, q, BB * TT, DM, DM);
    add_ln_k<0><<<BB * TT / 4, 256, 0, stream>>>(q, emb, g_i, b_i, nullptr, attn, attnb);

    // FFN
    gemm128_k<1><<<dim3(HF / 128, BB * TT / 128), 256, 0, stream>>>(
        attnb, W1t_i, b1_i, nullptr, nullptr, nullptr, nullptr, nullptr, f1b, BB * TT, HF, DM);
    gemmN64_k<<<dim3(DM / 64, BB * TT / 128), 256, 0, stream>>>(
        f1b, W2t_i, b2_i, k, BB * TT, DM, HF);

    if (i == NL - 1) {
      add_ln_k<0><<<BB * TT / 4, 256, 0, stream>>>(k, attn, g_i, b_i, nullptr, (float*)d_out, nullptr);
    } else {
      add_ln_k<1><<<BB * TT / 4, 256, 0, stream>>>(k, attn, g_i, b_i, posS, emb, embb);
    }
  }
}